// Round 9
// baseline (516.545 us; speedup 1.0000x reference)
//
#include <hip/hip_runtime.h>
#include <hip/hip_bf16.h>
#include <stdint.h>

#define IGNORE_INDEX (-100)

typedef float f32x4 __attribute__((ext_vector_type(4)));
typedef int i32x4 __attribute__((ext_vector_type(4)));
typedef int i32x16 __attribute__((ext_vector_type(16)));

constexpr int NTOK = 4096;
constexpr int HID  = 2048;
constexpr int VOC  = 32000;
constexpr int BM = 128, BN = 128, BKB = 64;   // BKB = K-bytes per tile (64 i8)
constexpr int NT_N = VOC / BN;   // 250 n-tiles
constexpr int NT_M = NTOK / BM;  // 32 m-tiles

// Integer quantization (int32 accumulate is exact; descale in epilogue):
//   X stored as i8(rne(X * 16)),  W stored as i8(rne(W * 1024))
#define XSCALE 16.0f
#define WSCALE 1024.0f
#define INV_SCALE (1.0f / 16384.0f)

// ---- ws layout (bytes) ----
// Wi8  @ 0         : 32000*2048 = 65,536,000
// Xi8  @ 65536000  :  4096*2048 =  8,388,608
// pmax @ 73924608  : 250*4096*4 =  4,096,000   ([ntile][row])
// psum @ 78020608  : 250*4096*4 =  4,096,000
// xt   @ 82116608  :     4096*4
// loss @ 82132992  :     4096*4

__device__ __forceinline__ unsigned q8(float v, float s) {
  int q = __float2int_rn(v * s);
  q = max(-127, min(127, q));
  return (unsigned)(q & 0xff);
}

__device__ __forceinline__ unsigned pack4(float4 a, float s) {
  return q8(a.x, s) | (q8(a.y, s) << 8) | (q8(a.z, s) << 16) | (q8(a.w, s) << 24);
}

__global__ void cvti8_kernel(const float* __restrict__ src, uint2* __restrict__ dst,
                             size_t n8, float scale) {
  size_t i = (size_t)blockIdx.x * blockDim.x + threadIdx.x;
  size_t stride = (size_t)gridDim.x * blockDim.x;
  const float4* s4 = reinterpret_cast<const float4*>(src);
  for (; i < n8; i += stride) {
    float4 a = s4[2 * i];
    float4 b = s4[2 * i + 1];
    dst[i] = make_uint2(pack4(a, scale), pack4(b, scale));
  }
}

// x_t[row] = dot(X[row], W[target[row]]) + bias[target[row]]   (fp32, exact)
__global__ void xt_kernel(const float* __restrict__ X, const float* __restrict__ W,
                          const float* __restrict__ bias, const int* __restrict__ tgt,
                          float* __restrict__ xt) {
  int row = blockIdx.x * 4 + (threadIdx.x >> 6);
  int lane = threadIdx.x & 63;
  if (row >= NTOK) return;
  int t = tgt[row];
  if (t < 0 || t >= VOC) { if (lane == 0) xt[row] = 0.0f; return; }
  const float4* xr = reinterpret_cast<const float4*>(X + (size_t)row * HID);
  const float4* wr = reinterpret_cast<const float4*>(W + (size_t)t * HID);
  float s = 0.0f;
  for (int i = lane; i < HID / 4; i += 64) {
    float4 a = xr[i], b = wr[i];
    s += a.x * b.x + a.y * b.y + a.z * b.z + a.w * b.w;
  }
#pragma unroll
  for (int d = 1; d < 64; d <<= 1) s += __shfl_xor(s, d);
  if (lane == 0) xt[row] = s + bias[t];
}

// Fused i8 GEMM (logits tile) + per-row (max, sumexp) partials.
// R8's m97 structure with BYTE-IDENTICAL LDS geometry (measured 0 conflicts,
// 3 blocks/CU): 128x128 tile, 4 waves 2x2, single-buffered 16KB LDS,
// 2 __syncthreads/K-iter, global_load_lds w=16, 32 K-iters (64B = 64 i8 rows).
// Compute: mfma_i32_32x32x32_i8 (2x bf16/fp8 rate, m55) — wave tile 64x64 as
// 2x2 of 32x32, 2 k-steps per iter => 8 MFMA/iter, acc i32x16[2][2] (exact).
// Operand layout: lane holds row (lane&31), 16B k-chunk (step*2 + (lane>>5));
// within-chunk k-permutation identical for A and B => dot invariant.
// Swizzle (both-sides): stored 16B-chunk s = c ^ ((row>>1)&3); 8-lane-pass
// audit: slots {0,4,1,5,2,6,3,7} distinct => conflict-free.
__global__ __launch_bounds__(256, 3) void gemm_lse_kernel(
    const uint8_t* __restrict__ Xi8, const uint8_t* __restrict__ Wi8,
    const float* __restrict__ bias,
    float* __restrict__ pmax, float* __restrict__ psum) {
  __shared__ __align__(16) uint8_t As[BM * BKB];   // 8 KB
  __shared__ __align__(16) uint8_t Bs[BN * BKB];   // 8 KB
  __shared__ float redM[2][BM];
  __shared__ float redS[2][BM];

  // XCD-chunked swizzle, mtile-fastest (8000 % 8 == 0, bijective)
  const int nwg = NT_M * NT_N;           // 8000
  const int xcd = blockIdx.x & 7;
  const int pos = blockIdx.x >> 3;
  const int wgid = xcd * (nwg >> 3) + pos;
  const int mtile = wgid & (NT_M - 1);   // 32 consecutive blocks share W panel
  const int ntile = wgid >> 5;
  const int mbase = mtile * BM;
  const int nbase = ntile * BN;

  const int tid = threadIdx.x;
  const int w = tid >> 6;                // 0..3
  const int lane = tid & 63;
  const int wr = w >> 1, wc = w & 1;     // wave -> 64x64 output sub-tile
  const int l31 = lane & 31;
  const int kh  = lane >> 5;             // k-chunk half (0/1)

  // ---- staging: linear LDS dest, inverse-swizzled global source ----
  // issue j: LDS bytes [j*4096 + tid*16, +16) -> row = j*64 + (tid>>2),
  // stored slot s = tid&3 holds global 16B-chunk c = s ^ ((row>>1)&3)
  //                                               = s ^ ((tid>>3)&3).
  const int srow = tid >> 2;                          // 0..63
  const int csrc = (tid & 3) ^ ((tid >> 3) & 3);
  const uint8_t* aSt0 = Xi8 + (size_t)(mbase + srow) * HID + csrc * 16;
  const uint8_t* aSt1 = aSt0 + (size_t)64 * HID;      // j=1: +64 rows
  const uint8_t* bSt0 = Wi8 + (size_t)(nbase + srow) * HID + csrc * 16;
  const uint8_t* bSt1 = bSt0 + (size_t)64 * HID;

  // ds_read: row r = (wr|wc)*64 + mi*32 + l31; global chunk c = step*2 + kh,
  // stored at c ^ ((r>>1)&3); (r>>1)&3 = (l31>>1)&3 (64/32-multiples drop out).
  const int g = (l31 >> 1) & 3;
  const int slot0 = (0 + kh) ^ g;        // step 0: chunk kh
  const int slot1 = (2 + kh) ^ g;        // step 1: chunk 2+kh
  const int arow0 = (wr * 64 + l31) * BKB;
  const int brow0 = (wc * 64 + l31) * BKB;

  i32x16 acc[2][2];
#pragma unroll
  for (int mi = 0; mi < 2; ++mi)
#pragma unroll
    for (int ni = 0; ni < 2; ++ni)
#pragma unroll
      for (int j = 0; j < 16; ++j) acc[mi][ni][j] = 0;

  float bv[2];
#pragma unroll
  for (int ni = 0; ni < 2; ++ni) bv[ni] = bias[nbase + wc * 64 + ni * 32 + l31];

#define GLDS(SRC, DST)                                                              \
  __builtin_amdgcn_global_load_lds((const __attribute__((address_space(1))) void*)(SRC), \
                                   (__attribute__((address_space(3))) void*)(DST), 16, 0, 0)

  for (int k0 = 0; k0 < HID; k0 += BKB) {
    __syncthreads();
    GLDS(aSt0 + k0, As + tid * 16);
    GLDS(aSt1 + k0, As + 4096 + tid * 16);
    GLDS(bSt0 + k0, Bs + tid * 16);
    GLDS(bSt1 + k0, Bs + 4096 + tid * 16);
    __syncthreads();

    i32x4 a0[2], a1[2], b0[2], b1[2];
#pragma unroll
    for (int mi = 0; mi < 2; ++mi) {
      const uint8_t* p = As + arow0 + mi * 32 * BKB;
      a0[mi] = *reinterpret_cast<const i32x4*>(p + slot0 * 16);
      a1[mi] = *reinterpret_cast<const i32x4*>(p + slot1 * 16);
    }
#pragma unroll
    for (int ni = 0; ni < 2; ++ni) {
      const uint8_t* p = Bs + brow0 + ni * 32 * BKB;
      b0[ni] = *reinterpret_cast<const i32x4*>(p + slot0 * 16);
      b1[ni] = *reinterpret_cast<const i32x4*>(p + slot1 * 16);
    }
#pragma unroll
    for (int mi = 0; mi < 2; ++mi)
#pragma unroll
      for (int ni = 0; ni < 2; ++ni) {
        acc[mi][ni] = __builtin_amdgcn_mfma_i32_32x32x32_i8(
            a0[mi], b0[ni], acc[mi][ni], 0, 0, 0);
        acc[mi][ni] = __builtin_amdgcn_mfma_i32_32x32x32_i8(
            a1[mi], b1[ni], acc[mi][ni], 0, 0, 0);
      }
  }
#undef GLDS

  // ---- epilogue: per-row (max, sumexp) over this block's 128 cols ----
  // 32x32 C/D layout (m74/m101-verified): col = lane&31,
  // row = (reg&3) + 8*(reg>>2) + 4*(lane>>5). Descale 1/16384 + bias.
#pragma unroll
  for (int mi = 0; mi < 2; ++mi) {
#pragma unroll
    for (int j = 0; j < 16; ++j) {
      float v0 = fmaf((float)acc[mi][0][j], INV_SCALE, bv[0]);
      float v1 = fmaf((float)acc[mi][1][j], INV_SCALE, bv[1]);
      float mx = fmaxf(v0, v1);
#pragma unroll
      for (int d = 1; d < 32; d <<= 1) mx = fmaxf(mx, __shfl_xor(mx, d));
      float s = __expf(v0 - mx) + __expf(v1 - mx);
#pragma unroll
      for (int d = 1; d < 32; d <<= 1) s += __shfl_xor(s, d);
      if (l31 == 0) {
        int lr = wr * 64 + mi * 32 + (j & 3) + 8 * (j >> 2) + 4 * kh;
        redM[wc][lr] = mx;
        redS[wc][lr] = s;
      }
    }
  }
  __syncthreads();
  if (tid < BM) {
    float m0 = redM[0][tid], m1 = redM[1][tid];
    float M = fmaxf(m0, m1);
    float S = __expf(m0 - M) * redS[0][tid] + __expf(m1 - M) * redS[1][tid];
    size_t row = (size_t)mbase + tid;
    pmax[(size_t)ntile * NTOK + row] = M;   // coalesced over tid
    psum[(size_t)ntile * NTOK + row] = S;
  }
}

// merge 250 partials per row -> lse -> per-row loss
__global__ void lse_kernel(const float* __restrict__ pmax, const float* __restrict__ psum,
                           const float* __restrict__ xt, const int* __restrict__ tgt,
                           float* __restrict__ loss) {
  int row = blockIdx.x * 4 + (threadIdx.x >> 6);
  int lane = threadIdx.x & 63;
  if (row >= NTOK) return;
  float M = -3.4e38f;
  for (int i = lane; i < NT_N; i += 64) M = fmaxf(M, pmax[(size_t)i * NTOK + row]);
#pragma unroll
  for (int d = 1; d < 64; d <<= 1) M = fmaxf(M, __shfl_xor(M, d));
  float S = 0.0f;
  for (int i = lane; i < NT_N; i += 64)
    S += __expf(pmax[(size_t)i * NTOK + row] - M) * psum[(size_t)i * NTOK + row];
#pragma unroll
  for (int d = 1; d < 64; d <<= 1) S += __shfl_xor(S, d);
  if (lane == 0) {
    int tg = tgt[row];
    bool valid = (tg != IGNORE_INDEX);
    float lse = M + __logf(S);
    loss[row] = valid ? (lse - xt[row]) : 0.0f;
  }
}

__global__ void final_kernel(const float* __restrict__ loss, const int* __restrict__ tgt,
                             float* __restrict__ out) {
  __shared__ float shs[256];
  __shared__ float shc[256];
  int tid = threadIdx.x;
  float s = 0.0f, c = 0.0f;
  for (int i = tid; i < NTOK; i += 256) {
    s += loss[i];
    c += (tgt[i] != IGNORE_INDEX) ? 1.0f : 0.0f;
  }
  shs[tid] = s; shc[tid] = c;
  __syncthreads();
  for (int off = 128; off > 0; off >>= 1) {
    if (tid < off) { shs[tid] += shs[tid + off]; shc[tid] += shc[tid + off]; }
    __syncthreads();
  }
  if (tid == 0) out[0] = shs[0] / fmaxf(shc[0], 1.0f);
}

extern "C" void kernel_launch(void* const* d_in, const int* in_sizes, int n_in,
                              void* d_out, int out_size, void* d_ws, size_t ws_size,
                              hipStream_t stream) {
  const float* W    = (const float*)d_in[0];  // [32000][2048]
  const float* X    = (const float*)d_in[1];  // [4096][2048]
  const int*   tgt  = (const int*)d_in[2];    // [4096]
  const float* bias = (const float*)d_in[3];  // [32000]
  float* out = (float*)d_out;

  char* ws = (char*)d_ws;
  uint8_t* Wi8 = (uint8_t*)(ws);
  uint8_t* Xi8 = (uint8_t*)(ws + 65536000);
  float* pmax  = (float*)  (ws + 73924608);
  float* psum  = (float*)  (ws + 78020608);
  float* xt    = (float*)  (ws + 82116608);
  float* loss  = (float*)  (ws + 82132992);

  cvti8_kernel<<<2048, 256, 0, stream>>>(W, (uint2*)Wi8, (size_t)VOC * HID / 8, WSCALE);
  cvti8_kernel<<<1024, 256, 0, stream>>>(X, (uint2*)Xi8, (size_t)NTOK * HID / 8, XSCALE);
  xt_kernel<<<NTOK / 4, 256, 0, stream>>>(X, W, bias, tgt, xt);
  gemm_lse_kernel<<<NT_M * NT_N, 256, 0, stream>>>(Xi8, Wi8, bias, pmax, psum);
  lse_kernel<<<NTOK / 4, 256, 0, stream>>>(pmax, psum, xt, tgt, loss);
  final_kernel<<<1, 256, 0, stream>>>(loss, tgt, out);
}

// Round 10
// 440.512 us; speedup vs baseline: 1.1726x; 1.1726x over previous
//
#include <hip/hip_runtime.h>
#include <hip/hip_bf16.h>
#include <stdint.h>

#define IGNORE_INDEX (-100)

typedef float f32x4 __attribute__((ext_vector_type(4)));
typedef int i32x4 __attribute__((ext_vector_type(4)));

constexpr int NTOK = 4096;
constexpr int HID  = 2048;
constexpr int VOC  = 32000;
constexpr int BM = 128, BN = 128, BKB = 64;   // BKB = K-bytes per tile (64 i8)
constexpr int NT_N = VOC / BN;   // 250 n-tiles
constexpr int NT_M = NTOK / BM;  // 32 m-tiles

// Integer quantization (int32 accumulate is exact; descale in epilogue):
//   X stored as i8(rne(X * 16)),  W stored as i8(rne(W * 1024))
#define XSCALE 16.0f
#define WSCALE 1024.0f
#define INV_SCALE (1.0f / 16384.0f)

// ---- ws layout (bytes) ----
// Wi8  @ 0         : 32000*2048 = 65,536,000
// Xi8  @ 65536000  :  4096*2048 =  8,388,608
// pmax @ 73924608  : 250*4096*4 =  4,096,000   ([ntile][row])
// psum @ 78020608  : 250*4096*4 =  4,096,000
// xt   @ 82116608  :     4096*4
// loss @ 82132992  :     4096*4

__device__ __forceinline__ unsigned q8(float v, float s) {
  int q = __float2int_rn(v * s);
  q = max(-127, min(127, q));
  return (unsigned)(q & 0xff);
}

__device__ __forceinline__ unsigned pack4(float4 a, float s) {
  return q8(a.x, s) | (q8(a.y, s) << 8) | (q8(a.z, s) << 16) | (q8(a.w, s) << 24);
}

__global__ void cvti8_kernel(const float* __restrict__ src, uint2* __restrict__ dst,
                             size_t n8, float scale) {
  size_t i = (size_t)blockIdx.x * blockDim.x + threadIdx.x;
  size_t stride = (size_t)gridDim.x * blockDim.x;
  const float4* s4 = reinterpret_cast<const float4*>(src);
  for (; i < n8; i += stride) {
    float4 a = s4[2 * i];
    float4 b = s4[2 * i + 1];
    dst[i] = make_uint2(pack4(a, scale), pack4(b, scale));
  }
}

// x_t[row] = dot(X[row], W[target[row]]) + bias[target[row]]   (fp32, exact)
__global__ void xt_kernel(const float* __restrict__ X, const float* __restrict__ W,
                          const float* __restrict__ bias, const int* __restrict__ tgt,
                          float* __restrict__ xt) {
  int row = blockIdx.x * 4 + (threadIdx.x >> 6);
  int lane = threadIdx.x & 63;
  if (row >= NTOK) return;
  int t = tgt[row];
  if (t < 0 || t >= VOC) { if (lane == 0) xt[row] = 0.0f; return; }
  const float4* xr = reinterpret_cast<const float4*>(X + (size_t)row * HID);
  const float4* wr = reinterpret_cast<const float4*>(W + (size_t)t * HID);
  float s = 0.0f;
  for (int i = lane; i < HID / 4; i += 64) {
    float4 a = xr[i], b = wr[i];
    s += a.x * b.x + a.y * b.y + a.z * b.z + a.w * b.w;
  }
#pragma unroll
  for (int d = 1; d < 64; d <<= 1) s += __shfl_xor(s, d);
  if (lane == 0) xt[row] = s + bias[t];
}

// Fused i8 GEMM (logits tile) + per-row (max, sumexp) partials.
// BYTE-IDENTICAL LDS geometry to R8's fp8 kernel (measured 0 conflicts):
// 128x128 tile, 4 waves 2x2, single-buffered 16KB LDS, 2 __syncthreads/K-iter,
// global_load_lds w=16, 32 K-iters (rows = 64B). Only the compute changes:
// mfma_i32_16x16x64_i8 — K=64 covers the whole row, ONE MFMA per (mi,ni),
// 2x the fp8 rate (m16: 3944 TOPS). Fragment = one b128 at the SAME address
// R8 read (row=l15 16-lane groups, chunk=kgrp, pair-XOR swizzle) — the only
// read geometry measured conflict-free on this HW (R3/R7/R9 all +4cyc/read).
// A/B lane maps are symmetric => any internal k-order cancels in the dot.
// 4 blocks/CU (VGPR ~64, LDS 18KB): extra TLP to hide the barrier drain.
__global__ __launch_bounds__(256, 4) void gemm_lse_kernel(
    const uint8_t* __restrict__ Xi8, const uint8_t* __restrict__ Wi8,
    const float* __restrict__ bias,
    float* __restrict__ pmax, float* __restrict__ psum) {
  __shared__ __align__(16) uint8_t As[BM * BKB];   // 8 KB
  __shared__ __align__(16) uint8_t Bs[BN * BKB];   // 8 KB
  __shared__ float redM[2][BM];
  __shared__ float redS[2][BM];

  // XCD-chunked swizzle, mtile-fastest (8000 % 8 == 0, bijective)
  const int nwg = NT_M * NT_N;           // 8000
  const int xcd = blockIdx.x & 7;
  const int pos = blockIdx.x >> 3;
  const int wgid = xcd * (nwg >> 3) + pos;
  const int mtile = wgid & (NT_M - 1);   // 32 consecutive blocks share W panel
  const int ntile = wgid >> 5;
  const int mbase = mtile * BM;
  const int nbase = ntile * BN;

  const int tid = threadIdx.x;
  const int w = tid >> 6;                // 0..3
  const int lane = tid & 63;
  const int wr = w >> 1, wc = w & 1;     // wave -> 64x64 output sub-tile
  const int l15 = lane & 15;
  const int kgrp = lane >> 4;            // 0..3

  // ---- staging: linear LDS dest, inverse-swizzled global source ----
  // issue j: LDS bytes [j*4096 + tid*16, +16) -> row = j*64 + (tid>>2),
  // stored slot s = tid&3 holds global 16B-chunk c = s ^ ((row>>1)&3)
  //                                               = s ^ ((tid>>3)&3).
  const int srow = tid >> 2;                          // 0..63
  const int csrc = (tid & 3) ^ ((tid >> 3) & 3);
  const uint8_t* aSt0 = Xi8 + (size_t)(mbase + srow) * HID + csrc * 16;
  const uint8_t* aSt1 = aSt0 + (size_t)64 * HID;      // j=1: +64 rows
  const uint8_t* bSt0 = Wi8 + (size_t)(nbase + srow) * HID + csrc * 16;
  const uint8_t* bSt1 = bSt0 + (size_t)64 * HID;

  // ds_read: row r, global chunk kgrp stored at kgrp ^ ((r>>1)&3);
  // (r>>1)&3 = (l15>>1)&3 for our rows (wr*64, wc*64, mi*16 all ≡ 0 mod 16).
  const int swz16 = (kgrp ^ ((l15 >> 1) & 3)) * 16;   // byte offset in row
  const int arow0 = wr * 64 + l15;
  const int brow0 = wc * 64 + l15;

  i32x4 acc[4][4];
#pragma unroll
  for (int mi = 0; mi < 4; ++mi)
#pragma unroll
    for (int ni = 0; ni < 4; ++ni)
#pragma unroll
      for (int j = 0; j < 4; ++j) acc[mi][ni][j] = 0;

  float bv[4];
#pragma unroll
  for (int ni = 0; ni < 4; ++ni) bv[ni] = bias[nbase + wc * 64 + ni * 16 + l15];

#define GLDS(SRC, DST)                                                              \
  __builtin_amdgcn_global_load_lds((const __attribute__((address_space(1))) void*)(SRC), \
                                   (__attribute__((address_space(3))) void*)(DST), 16, 0, 0)

  for (int k0 = 0; k0 < HID; k0 += BKB) {
    __syncthreads();
    GLDS(aSt0 + k0, As + tid * 16);
    GLDS(aSt1 + k0, As + 4096 + tid * 16);
    GLDS(bSt0 + k0, Bs + tid * 16);
    GLDS(bSt1 + k0, Bs + 4096 + tid * 16);
    __syncthreads();

    i32x4 af[4], bg[4];
#pragma unroll
    for (int mi = 0; mi < 4; ++mi)
      af[mi] = *reinterpret_cast<const i32x4*>(As + (arow0 + mi * 16) * BKB + swz16);
#pragma unroll
    for (int ni = 0; ni < 4; ++ni)
      bg[ni] = *reinterpret_cast<const i32x4*>(Bs + (brow0 + ni * 16) * BKB + swz16);
#pragma unroll
    for (int mi = 0; mi < 4; ++mi)
#pragma unroll
      for (int ni = 0; ni < 4; ++ni)
        acc[mi][ni] = __builtin_amdgcn_mfma_i32_16x16x64_i8(
            af[mi], bg[ni], acc[mi][ni], 0, 0, 0);
  }
#undef GLDS

  // ---- epilogue: per-row (max, sumexp) over this block's 128 cols ----
  // C frag (16x16, dtype-independent): col = l15, row = kgrp*4 + j.
  // Descale 1/16384 folded into the bias FMA.
#pragma unroll
  for (int mi = 0; mi < 4; ++mi) {
#pragma unroll
    for (int j = 0; j < 4; ++j) {
      float v0 = fmaf((float)acc[mi][0][j], INV_SCALE, bv[0]);
      float v1 = fmaf((float)acc[mi][1][j], INV_SCALE, bv[1]);
      float v2 = fmaf((float)acc[mi][2][j], INV_SCALE, bv[2]);
      float v3 = fmaf((float)acc[mi][3][j], INV_SCALE, bv[3]);
      float mx = fmaxf(fmaxf(v0, v1), fmaxf(v2, v3));
#pragma unroll
      for (int d = 1; d < 16; d <<= 1) mx = fmaxf(mx, __shfl_xor(mx, d));
      float s = __expf(v0 - mx) + __expf(v1 - mx) + __expf(v2 - mx) + __expf(v3 - mx);
#pragma unroll
      for (int d = 1; d < 16; d <<= 1) s += __shfl_xor(s, d);
      if (l15 == 0) {
        int lr = wr * 64 + mi * 16 + kgrp * 4 + j;
        redM[wc][lr] = mx;
        redS[wc][lr] = s;
      }
    }
  }
  __syncthreads();
  if (tid < BM) {
    float m0 = redM[0][tid], m1 = redM[1][tid];
    float M = fmaxf(m0, m1);
    float S = __expf(m0 - M) * redS[0][tid] + __expf(m1 - M) * redS[1][tid];
    size_t row = (size_t)mbase + tid;
    pmax[(size_t)ntile * NTOK + row] = M;   // coalesced over tid
    psum[(size_t)ntile * NTOK + row] = S;
  }
}

// merge 250 partials per row -> lse -> per-row loss
__global__ void lse_kernel(const float* __restrict__ pmax, const float* __restrict__ psum,
                           const float* __restrict__ xt, const int* __restrict__ tgt,
                           float* __restrict__ loss) {
  int row = blockIdx.x * 4 + (threadIdx.x >> 6);
  int lane = threadIdx.x & 63;
  if (row >= NTOK) return;
  float M = -3.4e38f;
  for (int i = lane; i < NT_N; i += 64) M = fmaxf(M, pmax[(size_t)i * NTOK + row]);
#pragma unroll
  for (int d = 1; d < 64; d <<= 1) M = fmaxf(M, __shfl_xor(M, d));
  float S = 0.0f;
  for (int i = lane; i < NT_N; i += 64)
    S += __expf(pmax[(size_t)i * NTOK + row] - M) * psum[(size_t)i * NTOK + row];
#pragma unroll
  for (int d = 1; d < 64; d <<= 1) S += __shfl_xor(S, d);
  if (lane == 0) {
    int tg = tgt[row];
    bool valid = (tg != IGNORE_INDEX);
    float lse = M + __logf(S);
    loss[row] = valid ? (lse - xt[row]) : 0.0f;
  }
}

__global__ void final_kernel(const float* __restrict__ loss, const int* __restrict__ tgt,
                             float* __restrict__ out) {
  __shared__ float shs[256];
  __shared__ float shc[256];
  int tid = threadIdx.x;
  float s = 0.0f, c = 0.0f;
  for (int i = tid; i < NTOK; i += 256) {
    s += loss[i];
    c += (tgt[i] != IGNORE_INDEX) ? 1.0f : 0.0f;
  }
  shs[tid] = s; shc[tid] = c;
  __syncthreads();
  for (int off = 128; off > 0; off >>= 1) {
    if (tid < off) { shs[tid] += shs[tid + off]; shc[tid] += shc[tid + off]; }
    __syncthreads();
  }
  if (tid == 0) out[0] = shs[0] / fmaxf(shc[0], 1.0f);
}

extern "C" void kernel_launch(void* const* d_in, const int* in_sizes, int n_in,
                              void* d_out, int out_size, void* d_ws, size_t ws_size,
                              hipStream_t stream) {
  const float* W    = (const float*)d_in[0];  // [32000][2048]
  const float* X    = (const float*)d_in[1];  // [4096][2048]
  const int*   tgt  = (const int*)d_in[2];    // [4096]
  const float* bias = (const float*)d_in[3];  // [32000]
  float* out = (float*)d_out;

  char* ws = (char*)d_ws;
  uint8_t* Wi8 = (uint8_t*)(ws);
  uint8_t* Xi8 = (uint8_t*)(ws + 65536000);
  float* pmax  = (float*)  (ws + 73924608);
  float* psum  = (float*)  (ws + 78020608);
  float* xt    = (float*)  (ws + 82116608);
  float* loss  = (float*)  (ws + 82132992);

  cvti8_kernel<<<2048, 256, 0, stream>>>(W, (uint2*)Wi8, (size_t)VOC * HID / 8, WSCALE);
  cvti8_kernel<<<1024, 256, 0, stream>>>(X, (uint2*)Xi8, (size_t)NTOK * HID / 8, XSCALE);
  xt_kernel<<<NTOK / 4, 256, 0, stream>>>(X, W, bias, tgt, xt);
  gemm_lse_kernel<<<NT_M * NT_N, 256, 0, stream>>>(Xi8, Wi8, bias, pmax, psum);
  lse_kernel<<<NTOK / 4, 256, 0, stream>>>(pmax, psum, xt, tgt, loss);
  final_kernel<<<1, 256, 0, stream>>>(loss, tgt, out);
}